// Round 29
// baseline (52.971 us; speedup 1.0000x reference)
//
#include <hip/hip_runtime.h>
#include <math.h>

#define HW 262144   // 512*512
#define TAB_SPARSE_OFF 8193
#define FSUM_OFF 32768
#define TW 260      // tile width: 256 + 4 halo cols

__device__ __forceinline__ int clip511f(float t) { return (int)fminf(fmaxf(t, 0.0f), 511.0f); }

// exact f32 MLP logit (table build)
__device__ float mlp_lg(float t,
                        const float* __restrict__ w0, const float* __restrict__ s0,
                        const float* __restrict__ b0, const float* __restrict__ w1,
                        const float* __restrict__ s1, const float* __restrict__ b1,
                        const float* __restrict__ w2, const float* __restrict__ b2) {
    float h0[16];
    #pragma unroll
    for (int k = 0; k < 16; ++k)
        h0[k] = fmaxf((w0[k] * t) * s0[k] + b0[k], 0.0f);
    float lg = b2[0];
    #pragma unroll
    for (int j = 0; j < 8; ++j) {
        float a1 = 0.0f;
        #pragma unroll
        for (int k = 0; k < 16; ++k) a1 += w1[j * 16 + k] * h0[k];
        float h1 = fmaxf(a1 * s1[j] + b1[j], 0.0f);
        lg += w2[j] * h1;
    }
    return lg;
}

__global__ __launch_bounds__(256) void tab_kernel(
    const float* __restrict__ w0, const float* __restrict__ s0, const float* __restrict__ b0,
    const float* __restrict__ w1, const float* __restrict__ s1, const float* __restrict__ b1,
    const float* __restrict__ w2, const float* __restrict__ b2,
    float* __restrict__ ws) {
    int i = blockIdx.x * 256 + threadIdx.x;
    if (i <= 8192) {
        float t = -1024.0f + 0.25f * (float)i;
        ws[i] = mlp_lg(t, w0, s0, b0, w1, s1, b1, w2, b2);
    }
    int j = i - 8448;
    if (j >= 0 && j <= 8192) {
        float t = -131072.0f + 32.0f * (float)j;
        ws[TAB_SPARSE_OFF + j] = mlp_lg(t, w0, s0, b0, w1, s1, b1, w2, b2);
    }
}

__global__ __launch_bounds__(256) void fsum_kernel(const float* __restrict__ rf,
                                                   float* __restrict__ fsum) {
    int t = blockIdx.x * 256 + threadIdx.x;        // 0 .. 131071
    int b = t >> 16;
    int q = t & 65535;
    const float4* src = reinterpret_cast<const float4*>(rf) + (size_t)(b * 32) * 65536 + q;
    float4 acc = make_float4(0.f, 0.f, 0.f, 0.f);
    #pragma unroll
    for (int c = 0; c < 32; ++c) {
        float4 v = src[(size_t)c * 65536];
        acc.x += v.x; acc.y += v.y; acc.z += v.z; acc.w += v.w;
    }
    reinterpret_cast<float4*>(fsum)[t] = acc;
}

// Exact oracle axis chain (tree P=2305)
struct Axis { float wx, om; int c0, c1; };
__device__ __forceinline__ Axis axis_eval(int t_int) {
#pragma clang fp contract(off)
    const float RCP = (float)(1.0 / 255.5);
    float q = (float)t_int * RCP;
    float gp = (q - 1.0f) + 1.0f;
    float ix = ((gp * 512.0f) - 1.0f) * 0.5f;
    float x0 = floorf(ix);
    Axis a;
    a.wx = ix - x0;
    a.om = 1.0f - a.wx;
    a.c0 = clip511f(x0);
    a.c1 = clip511f(x0 + 1.0f);
    return a;
}

// ---------------- patch kernel: LDS-tiled gathers ----------------
// block = 256 consecutive pixels of one row (b, y, x in [bx, bx+255])
__global__ __launch_bounds__(256) void patch_kernel(
    const float* __restrict__ nrm, const float* __restrict__ dv,
    const float* __restrict__ intri, const float* __restrict__ ws,
    const float* __restrict__ w0, const float* __restrict__ s0, const float* __restrict__ b0,
    const float* __restrict__ w1, const float* __restrict__ s1, const float* __restrict__ b1,
    const float* __restrict__ w2, const float* __restrict__ b2,
    float* __restrict__ out)
{
    __shared__ float tile[4 * 4 * TW];   // [ch][row][col], ch: 0..2 normals, 3 Fsum
    __shared__ float sW[201];

    int tid = threadIdx.x;
    int bid = blockIdx.x;                 // 0 .. 2047
    int b = bid >> 10;
    int rowblk = bid & 1023;
    int y = rowblk >> 1;
    int bx = (rowblk & 1) << 8;
    int x = bx + tid;
    int r = y * 512 + x;

    int ry_base = y - 1;
    int cx_base = bx - 2;

    if (tid < 201) {
        float vv;
        if      (tid < 16)  vv = w0[tid];
        else if (tid < 32)  vv = s0[tid - 16];
        else if (tid < 48)  vv = b0[tid - 32];
        else if (tid < 176) vv = w1[tid - 48];
        else if (tid < 184) vv = s1[tid - 176];
        else if (tid < 192) vv = b1[tid - 184];
        else if (tid < 200) vv = w2[tid - 192];
        else                vv = b2[0];
        sW[tid] = vv;
    }

    // cooperative tile load: 4 ch × 4 rows × 260 cols, coalesced
    const float* fsum_b = ws + FSUM_OFF + (size_t)b * HW;
    const float* nrm_b  = nrm + (size_t)(b * 3) * HW;
    for (int idx = tid; idx < 4 * 4 * TW; idx += 256) {
        int ch  = idx / (4 * TW);
        int rem = idx - ch * 4 * TW;
        int row = rem / TW;
        int col = rem - row * TW;
        int ir = min(max(ry_base + row, 0), 511);
        int ic = min(max(cx_base + col, 0), 511);
        float vsrc = (ch < 3) ? nrm_b[(size_t)ch * HW + ir * 512 + ic]
                              : fsum_b[ir * 512 + ic];
        tile[idx] = vsrc;
    }
    __syncthreads();

    float fx = intri[b * 9 + 0], cx = intri[b * 9 + 2];
    float fy = intri[b * 9 + 4], cy = intri[b * 9 + 5];

    // axes
    Axis axm = axis_eval(x - 1);
    Axis ax0 = axis_eval(x);
    Axis axp = axis_eval(x + 1);
    Axis ay0 = axis_eval(y);
    Axis ayp = axis_eval(y + 1);

    // taps: n0=(ax0,ayp), n1=(axm,ay0), n2=(ax0,ay0), n3=(axp,ay0)
    float wxt[4]  = { ax0.wx, axm.wx, ax0.wx, axp.wx };
    float omxt[4] = { ax0.om, axm.om, ax0.om, axp.om };
    float wyt[4]  = { ayp.wx, ay0.wx, ay0.wx, ay0.wx };
    float omyt[4] = { ayp.om, ay0.om, ay0.om, ay0.om };
    int xc0[4] = { ax0.c0, axm.c0, ax0.c0, axp.c0 };
    int xc1[4] = { ax0.c1, axm.c1, ax0.c1, axp.c1 };
    int yc0[4] = { ayp.c0, ay0.c0, ay0.c0, ay0.c0 };
    int yc1[4] = { ayp.c1, ay0.c1, ay0.c1, ay0.c1 };

    // LDS tile offsets for the 4 corners of each tap
    int o00[4], o01[4], o10[4], o11[4];
    #pragma unroll
    for (int n = 0; n < 4; ++n) {
        int tc0 = xc0[n] - cx_base, tc1 = xc1[n] - cx_base;
        int tr0 = yc0[n] - ry_base, tr1 = yc1[n] - ry_base;
        o00[n] = tr0 * TW + tc0; o01[n] = tr0 * TW + tc1;
        o10[n] = tr1 * TW + tc0; o11[n] = tr1 * TW + tc1;
    }

    // center normals from tile (exact copies of nrm values)
    int ctr = 1 * TW + (tid + 2);
    float nx = tile[ctr];
    float ny = tile[4 * TW + ctr];
    float nz = tile[8 * TW + ctr];

    size_t dvbase = (size_t)(b * 8) * HW + (size_t)r;
    float dvv[8];
    #pragma unroll
    for (int d = 0; d < 8; ++d) dvv[d] = dv[dvbase + (size_t)d * HW];

    // ---- geometry (ε-critical trees, verbatim) ----
    float sim[5], F[5], ss, wv[5];
    {
#pragma clang fp contract(off)
        float u[5], v[5];
        float nbn = sqrtf((nx * nx + ny * ny) + nz * nz);

        for (int n = 0; n < 4; ++n) {
            float wxf = wxt[n], omx = omxt[n], wyf = wyt[n], omy = omyt[n];
            int x0 = xc0[n], x1 = xc1[n], y0 = yc0[n], y1 = yc1[n];

            // xy coordinate sample — exact flat tree
            {
                float m00 = (float)x0 * omx, m01 = (float)x1 * wxf;
                float m10 = (float)x0 * omx, m11 = (float)x1 * wxf;
                float A = m00 * omy, B = m01 * omy, C = m10 * wyf, D = m11 * wyf;
                float xs_ = ((A + B) + C) + D;
                float n00 = (float)y0 * omx, n01 = (float)y0 * wxf;
                float n10 = (float)y1 * omx, n11 = (float)y1 * wxf;
                float A2 = n00 * omy, B2 = n01 * omy, C2 = n10 * wyf, D2 = n11 * wyf;
                float ys_ = ((A2 + B2) + C2) + D2;
                u[n] = (xs_ - cx) / fx;
                v[n] = (ys_ - cy) / fy;
            }

            // normals bilinear — exact flat tree (values from LDS tile)
            float nsx, nsy, nsz;
            {
                float m00 = tile[o00[n]] * omx, m01 = tile[o01[n]] * wxf;
                float m10 = tile[o10[n]] * omx, m11 = tile[o11[n]] * wxf;
                nsx = ((m00 * omy + m01 * omy) + m10 * wyf) + m11 * wyf;
                float p00 = tile[4*TW + o00[n]] * omx, p01 = tile[4*TW + o01[n]] * wxf;
                float p10 = tile[4*TW + o10[n]] * omx, p11 = tile[4*TW + o11[n]] * wxf;
                nsy = ((p00 * omy + p01 * omy) + p10 * wyf) + p11 * wyf;
                float q00 = tile[8*TW + o00[n]] * omx, q01 = tile[8*TW + o01[n]] * wxf;
                float q10 = tile[8*TW + o10[n]] * omx, q11 = tile[8*TW + o11[n]] * wxf;
                nsz = ((q00 * omy + q01 * omy) + q10 * wyf) + q11 * wyf;
            }

            float dot = (nsx * nx + nsy * ny) + nsz * nz;
            float na  = sqrtf((nsx * nsx + nsy * nsy) + nsz * nsz);
            sim[n] = dot / (fmaxf(na, 1e-8f) * fmaxf(nbn, 1e-8f));   // ε-critical

            float m00 = tile[12*TW + o00[n]] * omx, m01 = tile[12*TW + o01[n]] * wxf;
            float m10 = tile[12*TW + o10[n]] * omx, m11 = tile[12*TW + o11[n]] * wxf;
            F[n] = ((m00 * omy + m01 * omy) + m10 * wyf) + m11 * wyf;
        }
        u[4] = u[0]; v[4] = v[0]; sim[4] = sim[0]; F[4] = F[0];

        ss = ((sim[0] + sim[1]) + (sim[2] + sim[3])) + sim[4];   // pairwise (ε-critical)

        float num = (nx * u[2] + ny * v[2]) + nz;
        for (int n = 0; n < 5; ++n) {
            float den = (nx * u[n] + ny * v[n]) + nz;   // ε-critical tree
            if (fabsf(den) < 1e-8f) den = (den < 0.0f) ? -1e-8f : 1e-8f;
            float w_ = num * __builtin_amdgcn_rcpf(den);
            if (!isfinite(w_)) w_ = 1.0f;
            wv[n] = w_;
        }
    }

    // smooth contraction
    float rss = __builtin_amdgcn_rcpf(ss);
    float qv[5];
    #pragma unroll
    for (int n = 0; n < 5; ++n) qv[n] = (sim[n] * rss) * F[n];

    float sv[8];
    #pragma unroll
    for (int dp = 0; dp < 8; ++dp) {
        float acc = 0.0f;
        #pragma unroll
        for (int n = 0; n < 5; ++n) {
            const int flat = n * 8 + dp;
            acc += qv[n] * (wv[flat % 5] * dvv[flat / 5]);
        }
        sv[dp] = acc * 0.03125f;
    }

    // vw via 2-level PWL table (exact MLP for |t| > 2^17)
    float mx = -1e30f;
    #pragma unroll
    for (int d = 0; d < 8; ++d) {
        float t = sv[d];
        float at = fabsf(t);
        float lg;
        if (at < 131072.0f) {
            bool dense = at < 1024.0f;
            const float* g = dense ? ws : (ws + TAB_SPARSE_OFF);
            float T0  = dense ? -1024.0f : -131072.0f;
            float inv = dense ? 4.0f : 0.03125f;
            float p = (t - T0) * inv;
            int idx = (int)p;
            float fr = p - (float)idx;
            float g0 = g[idx], g1 = g[idx + 1];
            lg = g0 + fr * (g1 - g0);
        } else {
            float h0[16];
            #pragma unroll
            for (int k = 0; k < 16; ++k)
                h0[k] = fmaxf((sW[k] * t) * sW[16 + k] + sW[32 + k], 0.0f);
            lg = sW[200];
            #pragma unroll
            for (int j = 0; j < 8; ++j) {
                float a1 = 0.0f;
                #pragma unroll
                for (int k = 0; k < 16; ++k) a1 += sW[48 + j * 16 + k] * h0[k];
                float h1 = fmaxf(a1 * sW[176 + j] + sW[184 + j], 0.0f);
                lg += sW[192 + j] * h1;
            }
        }
        mx = fmaxf(mx, lg);
    }
    float vw = 1.0f / (1.0f + expf(-mx));   // max_d sigmoid == sigmoid(max_d)

    #pragma unroll
    for (int d = 0; d < 8; ++d)
        out[dvbase + (size_t)d * HW] = sv[d] * vw;
}

extern "C" void kernel_launch(void* const* d_in, const int* in_sizes, int n_in,
                              void* d_out, int out_size, void* d_ws, size_t ws_size,
                              hipStream_t stream) {
    const float* rf    = (const float*)d_in[0];
    const float* nrm   = (const float*)d_in[1];
    const float* dv    = (const float*)d_in[2];
    const float* intri = (const float*)d_in[3];
    const float* w0    = (const float*)d_in[4];
    const float* s0    = (const float*)d_in[5];
    const float* b0    = (const float*)d_in[6];
    const float* w1    = (const float*)d_in[7];
    const float* s1    = (const float*)d_in[8];
    const float* b1    = (const float*)d_in[9];
    const float* w2    = (const float*)d_in[10];
    const float* b2    = (const float*)d_in[11];
    float* out = (float*)d_out;
    float* ws  = (float*)d_ws;

    tab_kernel<<<66, 256, 0, stream>>>(w0, s0, b0, w1, s1, b1, w2, b2, ws);
    fsum_kernel<<<512, 256, 0, stream>>>(rf, ws + FSUM_OFF);
    patch_kernel<<<2048, 256, 0, stream>>>(nrm, dv, intri, ws,
                                           w0, s0, b0, w1, s1, b1, w2, b2, out);
}